// Round 10
// baseline (181.700 us; speedup 1.0000x reference)
//
#include <hip/hip_runtime.h>

#define S_ 4096
#define B_ 2
#define E_ 768
#define H_ 12
#define D_ 64

typedef __attribute__((ext_vector_type(8))) short short8;
typedef __attribute__((ext_vector_type(4))) float f32x4;
typedef unsigned short u16;
typedef unsigned int u32;

__device__ __forceinline__ u16 f2bf(float f) {
  union { float f; u32 u; } v; v.f = f;
  u32 r = v.u + 0x7FFFu + ((v.u >> 16) & 1u);
  return (u16)(r >> 16);
}

__device__ __forceinline__ void gl_lds16(const void* g, void* l) {
  __builtin_amdgcn_global_load_lds((const __attribute__((address_space(1))) u32*)g,
                                   (__attribute__((address_space(3))) u32*)l, 16, 0, 0);
}

// Fused prep: bid<1728 -> wt[z][n][k] = W_z[k][n]; else x[m][:] = bf16(query row)
__global__ __launch_bounds__(256) void k_prep(const float* __restrict__ q,
                                              const float* __restrict__ w0,
                                              const float* __restrict__ w1,
                                              const float* __restrict__ w2,
                                              u16* __restrict__ x,
                                              u16* __restrict__ wt) {
  __shared__ float tile[32][33];
  const int bid = blockIdx.x;
  if (bid < 1728) {
    const int z = bid / 576, r = bid % 576;
    const int k0 = (r / 24) * 32, n0 = (r % 24) * 32;
    const float* w = z == 0 ? w0 : (z == 1 ? w1 : w2);
    const int tx = threadIdx.x & 31, ty = threadIdx.x >> 5;
#pragma unroll
    for (int i = 0; i < 4; i++)
      tile[ty + i * 8][tx] = w[(k0 + ty + i * 8) * 768 + n0 + tx];
    __syncthreads();
    u16* o = wt + (size_t)z * 768 * 768;
#pragma unroll
    for (int i = 0; i < 4; i++)
      o[(n0 + ty + i * 8) * 768 + k0 + tx] = f2bf(tile[tx][ty + i * 8]);
  } else {
    const int m = bid - 1728;           // 0..8191
    const int e = threadIdx.x * 4;
    if (e < 768) {
      const int b = m >> 12, s = m & 4095;
      const float4 v = *(const float4*)&q[((s << 1) + b) * 768 + e];
      ushort4 o;
      o.x = f2bf(v.x); o.y = f2bf(v.y); o.z = f2bf(v.z); o.w = f2bf(v.w);
      *(ushort4*)&x[m * 768 + e] = o;
    }
  }
}

// Fused QKV GEMM: C[m][n] = x[m][:] @ wt[n][:] + bias, n in [0,2304), z = n/768.
// 128x128 tile, BK=32, 4 waves of 64x64. Triple-buffered LDS, counted vmcnt(4)
// (2-ahead prefetch). At the 2-phase structural ceiling (~590 TF) — parked.
__global__ __launch_bounds__(256, 3) void k_gemm_qkv(
    const u16* __restrict__ x, const u16* __restrict__ wt,
    const float* __restrict__ bq, const float* __restrict__ bk,
    const float* __restrict__ bv,
    u16* __restrict__ qb, u16* __restrict__ kb, u16* __restrict__ vt) {
  // buf i at i*8192 u16: A 128x32 at +0, B 128x32 at +4096
  // epilogue reuses [0, 18432) as 4 wave-private [64][72] tiles
  __shared__ __align__(16) u16 smem[24576];
  const int tid = threadIdx.x;
  const int lane = tid & 63, wave = tid >> 6;
  const int wm = wave >> 1, wn = wave & 1;
  const int l15 = lane & 15, lg = lane >> 4;

  // grid 1152 = 8 XCD x (8 m-tiles x 18 n-tiles)
  const int bid = blockIdx.x;
  const int xcd = bid & 7, idx = bid >> 3;          // idx 0..143
  const int m0 = (xcd * 8 + idx / 18) * 128;
  const int n0g = (idx % 18) * 128;                 // 0..2176
  const int z = n0g / 768, j0 = n0g % 768;
  const u16* wz = wt + (size_t)z * 768 * 768;

  f32x4 acc[4][4] = {};

  auto stage = [&](int buf, int kt) {               // 4 gl_lds16 per thread
#pragma unroll
    for (int c = 0; c < 2; c++) {                   // A: 512 chunks
      int ci = c * 256 + tid;
      int row = ci >> 2, cp = ci & 3;
      int sc = cp ^ ((row >> 1) & 3);               // involution f(row)
      gl_lds16(&x[(size_t)(m0 + row) * 768 + kt + sc * 8],
               &smem[buf * 8192 + (c * 256 + wave * 64) * 8]);
    }
#pragma unroll
    for (int c = 0; c < 2; c++) {                   // B: 512 chunks
      int ci = c * 256 + tid;
      int row = ci >> 2, cp = ci & 3;
      int sc = cp ^ ((row >> 1) & 3);
      gl_lds16(&wz[(size_t)(j0 + row) * 768 + kt + sc * 8],
               &smem[buf * 8192 + 4096 + (c * 256 + wave * 64) * 8]);
    }
  };

  stage(0, 0);
  stage(1, 32);
  const int kc = lg ^ ((l15 >> 1) & 3);             // swizzled k-chunk for reads
  int cur = 0;
  for (int t = 0; t < 24; t++) {
    if (t < 23) { asm volatile("s_waitcnt vmcnt(4)" ::: "memory"); }
    else       { asm volatile("s_waitcnt vmcnt(0)" ::: "memory"); }
    __builtin_amdgcn_s_barrier();
    __builtin_amdgcn_sched_barrier(0);
    if (t < 22) {
      int st = cur + 2; if (st >= 3) st -= 3;
      stage(st, (t + 2) * 32);
    }
    const int base = cur * 8192;
    short8 a[4], b[4];
#pragma unroll
    for (int mf = 0; mf < 4; mf++)
      a[mf] = *(const short8*)&smem[base + (wm * 64 + mf * 16 + l15) * 32 + kc * 8];
#pragma unroll
    for (int nf = 0; nf < 4; nf++)
      b[nf] = *(const short8*)&smem[base + 4096 + (wn * 64 + nf * 16 + l15) * 32 + kc * 8];
#pragma unroll
    for (int mf = 0; mf < 4; mf++)
#pragma unroll
      for (int nf = 0; nf < 4; nf++)
        acc[mf][nf] = __builtin_amdgcn_mfma_f32_16x16x32_bf16(a[mf], b[nf], acc[mf][nf], 0, 0, 0);
    cur = (cur + 1 == 3) ? 0 : cur + 1;
  }
  __syncthreads();   // all MFMAs/reads of buf2 done before smem reuse

  // ---- epilogue: retile through wave-private LDS [64][72], 16B stores ----
  u16* ep = &smem[wave * 4608];
  const float* bias_p = (z == 0) ? bq : (z == 1 ? bk : bv);
  const float sc_ = (z == 0) ? 0.125f : 1.0f;
  const int r8 = lane >> 3, cn = lane & 7;
  if (z < 2) {
    u16* t = (z == 0) ? qb : kb;
#pragma unroll
    for (int mf = 0; mf < 4; mf++)
#pragma unroll
      for (int nf = 0; nf < 4; nf++) {
        float bias = bias_p[j0 + wn * 64 + nf * 16 + l15];
#pragma unroll
        for (int r = 0; r < 4; r++)
          ep[(mf * 16 + lg * 4 + r) * 72 + nf * 16 + l15] =
              f2bf((acc[mf][nf][r] + bias) * sc_);
      }
#pragma unroll
    for (int i = 0; i < 8; i++) {
      int rl = i * 8 + r8;                     // local m row 0..63
      short8 v = *(const short8*)&ep[rl * 72 + cn * 8];
      *(short8*)&t[(size_t)(m0 + wm * 64 + rl) * 768 + j0 + wn * 64 + cn * 8] = v;
    }
  } else {
    // build n-major tile [64 n][64 m] so the transposed vt store is contiguous
#pragma unroll
    for (int nf = 0; nf < 4; nf++) {
      float bias = bias_p[j0 + wn * 64 + nf * 16 + l15];
#pragma unroll
      for (int mf = 0; mf < 4; mf++) {
        ushort4 pk;
        pk.x = f2bf(acc[mf][nf][0] + bias);
        pk.y = f2bf(acc[mf][nf][1] + bias);
        pk.z = f2bf(acc[mf][nf][2] + bias);
        pk.w = f2bf(acc[mf][nf][3] + bias);
        *(ushort4*)&ep[(nf * 16 + l15) * 72 + mf * 16 + lg * 4] = pk;
      }
    }
#pragma unroll
    for (int i = 0; i < 8; i++) {
      int nl = i * 8 + r8;                     // local n row 0..63
      int n = j0 + wn * 64 + nl;
      int h = n >> 6, d = n & 63;
      const int bb = m0 >> 12, srow = m0 & 4095;
      short8 v = *(const short8*)&ep[nl * 72 + cn * 8];
      *(short8*)&vt[(((size_t)(bb * 12 + h) * 64 + d) << 12) +
                    srow + wm * 64 + cn * 8] = v;
    }
  }
}

// Banded attention, BARRIER-FREE: K/V read directly from global (L2-resident
// by XCD-grouped mapping: 3 (b,h) pairs = 3MB per XCD L2). No LDS staging --
// removes the per-tile vmcnt(0)+barrier convoy (guide mistake #7, m169).
// 4 waves/block, each wave owns 32 q-rows and iterates its OWN 9-tile window.
// LDS: only the wave-private P relayout buffer (no sync needed on it).
// qb/kb: [b*S+s][h*64+d] bf16 ; vt: [((b*12+h)*64+d)][s] bf16 ; out: (S,B,E) f32
__global__ __launch_bounds__(256) void k_attn(const u16* __restrict__ qb,
                                              const u16* __restrict__ kb,
                                              const u16* __restrict__ vt,
                                              float* __restrict__ out) {
  __shared__ __align__(16) u16 pl[4][32 * 72];
  const int tid = threadIdx.x;
  const int lane = tid & 63, wave = tid >> 6;
  const int l15 = lane & 15, lg = lane >> 4;

  const int bid = blockIdx.x;            // 0..767
  const int xcd = bid & 7, i = bid >> 3; // i: 0..95
  const int pair = xcd * 3 + (i >> 5);   // 0..23
  const int chunk = i & 31;
  const int b = pair / 12, h = pair % 12;
  const int s0 = chunk * 128;
  const int q0 = s0 + wave * 32;

  const u16* kbase = kb + (size_t)(b << 12) * 768 + h * 64;
  const u16* vbase = vt + ((size_t)(b * 12 + h) << 18);   // *64*4096

  short8 qf[2][2];
#pragma unroll
  for (int mf = 0; mf < 2; mf++)
#pragma unroll
    for (int ks = 0; ks < 2; ks++)
      qf[mf][ks] = *(const short8*)&qb[(size_t)((b << 12) + q0 + mf * 16 + l15) * 768 +
                                       h * 64 + ks * 32 + lg * 8];

  f32x4 o[2][4] = {};
  float lsum[2][4] = {};

  // per-wave tile window (all tiles active for this wave)
  int lo = q0 - 256; if (lo < 0) lo = 0; lo &= ~63;
  int hi = q0 + 31 + 256; if (hi > S_ - 1) hi = S_ - 1;

  u16* plw = pl[wave];
  for (int kb0 = lo; kb0 <= hi; kb0 += 64) {
    // ---- K fragments straight from global (16 rows x 64B per load) ----
    short8 bkf[2][4];
#pragma unroll
    for (int ks = 0; ks < 2; ks++)
#pragma unroll
      for (int nf = 0; nf < 4; nf++)
        bkf[ks][nf] = *(const short8*)&kbase[(size_t)(kb0 + nf * 16 + l15) * 768 +
                                             ks * 32 + lg * 8];
    f32x4 sf[2][4] = {};
#pragma unroll
    for (int ks = 0; ks < 2; ks++)
#pragma unroll
      for (int mf = 0; mf < 2; mf++)
#pragma unroll
        for (int nf = 0; nf < 4; nf++)
          sf[mf][nf] = __builtin_amdgcn_mfma_f32_16x16x32_bf16(qf[mf][ks], bkf[ks][nf], sf[mf][nf], 0, 0, 0);
    // ---- band mask: only boundary tiles ----
    if (kb0 < q0 - 192 || kb0 > q0 + 192) {
#pragma unroll
      for (int mf = 0; mf < 2; mf++)
#pragma unroll
        for (int nf = 0; nf < 4; nf++) {
          int kj = kb0 + nf * 16 + l15;
#pragma unroll
          for (int r = 0; r < 4; r++) {
            int qi = q0 + mf * 16 + lg * 4 + r;
            if ((unsigned)(kj - qi + 256) > 512u) sf[mf][nf][r] = -3e38f;
          }
        }
    }
    // ---- softmax numerator (fixed m=0), per-lane partial l, P->LDS ----
#pragma unroll
    for (int mf = 0; mf < 2; mf++)
#pragma unroll
      for (int nf = 0; nf < 4; nf++)
#pragma unroll
        for (int r = 0; r < 4; r++) {
          float p = __expf(sf[mf][nf][r]);
          lsum[mf][r] += p;
          plw[(mf * 16 + lg * 4 + r) * 72 + nf * 16 + l15] = f2bf(p);
        }
    short8 pa[2][2];
#pragma unroll
    for (int mf = 0; mf < 2; mf++)
#pragma unroll
      for (int ks = 0; ks < 2; ks++)
        pa[mf][ks] = *(const short8*)&plw[(mf * 16 + l15) * 72 + ks * 32 + lg * 8];
    // ---- V fragments straight from global, then PV ----
#pragma unroll
    for (int ks = 0; ks < 2; ks++) {
      short8 bvf[4];
#pragma unroll
      for (int df = 0; df < 4; df++)
        bvf[df] = *(const short8*)&vbase[((size_t)(df * 16 + l15) << 12) +
                                         kb0 + ks * 32 + lg * 8];
#pragma unroll
      for (int mf = 0; mf < 2; mf++)
#pragma unroll
        for (int df = 0; df < 4; df++)
          o[mf][df] = __builtin_amdgcn_mfma_f32_16x16x32_bf16(pa[mf][ks], bvf[df], o[mf][df], 0, 0, 0);
    }
  }

  // deferred l reduction (over the 16 l15 lanes)
#pragma unroll
  for (int mf = 0; mf < 2; mf++)
#pragma unroll
    for (int r = 0; r < 4; r++) {
      float l = lsum[mf][r];
      l += __shfl_xor(l, 1); l += __shfl_xor(l, 2);
      l += __shfl_xor(l, 4); l += __shfl_xor(l, 8);
      lsum[mf][r] = l;
    }

  // epilogue: normalize and store (S,B,E) f32
#pragma unroll
  for (int mf = 0; mf < 2; mf++)
#pragma unroll
    for (int df = 0; df < 4; df++)
#pragma unroll
      for (int r = 0; r < 4; r++) {
        int s = q0 + mf * 16 + lg * 4 + r;
        out[(size_t)(s * 2 + b) * 768 + h * 64 + df * 16 + l15] =
            o[mf][df][r] / lsum[mf][r];
      }
}

extern "C" void kernel_launch(void* const* d_in, const int* in_sizes, int n_in,
                              void* d_out, int out_size, void* d_ws, size_t ws_size,
                              hipStream_t stream) {
  const float* query = (const float*)d_in[0];
  const float* Wq = (const float*)d_in[1];
  const float* bq = (const float*)d_in[2];
  const float* Wk = (const float*)d_in[3];
  const float* bk = (const float*)d_in[4];
  const float* Wv = (const float*)d_in[5];
  const float* bv = (const float*)d_in[6];
  float* out = (float*)d_out;

  char* ws = (char*)d_ws;
  size_t off = 0;
  auto alloc = [&](size_t bytes) {
    void* p = ws + off;
    off = (off + bytes + 255) & ~(size_t)255;
    return p;
  };
  u16* x  = (u16*)alloc((size_t)8192 * 768 * 2);
  u16* wt = (u16*)alloc((size_t)3 * 768 * 768 * 2);
  u16* qb = (u16*)alloc((size_t)8192 * 768 * 2);
  u16* kb = (u16*)alloc((size_t)8192 * 768 * 2);
  u16* vt = (u16*)alloc((size_t)8192 * 768 * 2);

  hipLaunchKernelGGL(k_prep, dim3(1728 + 8192), dim3(256), 0, stream,
                     query, Wq, Wk, Wv, x, wt);
  hipLaunchKernelGGL(k_gemm_qkv, dim3(1152), dim3(256), 0, stream,
                     x, wt, bq, bk, bv, qb, kb, vt);
  hipLaunchKernelGGL(k_attn, dim3(768), dim3(256), 0, stream, qb, kb, vt, out);
}

// Round 11
// 161.606 us; speedup vs baseline: 1.1243x; 1.1243x over previous
//
#include <hip/hip_runtime.h>

#define S_ 4096
#define B_ 2
#define E_ 768
#define H_ 12
#define D_ 64

typedef __attribute__((ext_vector_type(8))) short short8;
typedef __attribute__((ext_vector_type(4))) float f32x4;
typedef unsigned short u16;
typedef unsigned int u32;

__device__ __forceinline__ u16 f2bf(float f) {
  union { float f; u32 u; } v; v.f = f;
  u32 r = v.u + 0x7FFFu + ((v.u >> 16) & 1u);
  return (u16)(r >> 16);
}

__device__ __forceinline__ u16 f2bf_trunc(float f) {   // 1-op; for P>0 only
  union { float f; u32 u; } v; v.f = f;
  return (u16)(v.u >> 16);
}

__device__ __forceinline__ void gl_lds16(const void* g, void* l) {
  __builtin_amdgcn_global_load_lds((const __attribute__((address_space(1))) u32*)g,
                                   (__attribute__((address_space(3))) u32*)l, 16, 0, 0);
}

// Fused prep: bid<1728 -> wt[z][n][k] = W_z[k][n]; else x[m][:] = bf16(query row)
__global__ __launch_bounds__(256) void k_prep(const float* __restrict__ q,
                                              const float* __restrict__ w0,
                                              const float* __restrict__ w1,
                                              const float* __restrict__ w2,
                                              u16* __restrict__ x,
                                              u16* __restrict__ wt) {
  __shared__ float tile[32][33];
  const int bid = blockIdx.x;
  if (bid < 1728) {
    const int z = bid / 576, r = bid % 576;
    const int k0 = (r / 24) * 32, n0 = (r % 24) * 32;
    const float* w = z == 0 ? w0 : (z == 1 ? w1 : w2);
    const int tx = threadIdx.x & 31, ty = threadIdx.x >> 5;
#pragma unroll
    for (int i = 0; i < 4; i++)
      tile[ty + i * 8][tx] = w[(k0 + ty + i * 8) * 768 + n0 + tx];
    __syncthreads();
    u16* o = wt + (size_t)z * 768 * 768;
#pragma unroll
    for (int i = 0; i < 4; i++)
      o[(n0 + ty + i * 8) * 768 + k0 + tx] = f2bf(tile[tx][ty + i * 8]);
  } else {
    const int m = bid - 1728;           // 0..8191
    const int e = threadIdx.x * 4;
    if (e < 768) {
      const int b = m >> 12, s = m & 4095;
      const float4 v = *(const float4*)&q[((s << 1) + b) * 768 + e];
      ushort4 o;
      o.x = f2bf(v.x); o.y = f2bf(v.y); o.z = f2bf(v.z); o.w = f2bf(v.w);
      *(ushort4*)&x[m * 768 + e] = o;
    }
  }
}

// Fused QKV GEMM: C[m][n] = x[m][:] @ wt[n][:] + bias, n in [0,2304), z = n/768.
// 128x128 tile, BK=32, 4 waves of 64x64. Triple-buffered LDS, counted vmcnt(4)
// (2-ahead prefetch). At the 2-phase structural ceiling (~590 TF) — parked.
__global__ __launch_bounds__(256, 3) void k_gemm_qkv(
    const u16* __restrict__ x, const u16* __restrict__ wt,
    const float* __restrict__ bq, const float* __restrict__ bk,
    const float* __restrict__ bv,
    u16* __restrict__ qb, u16* __restrict__ kb, u16* __restrict__ vt) {
  // buf i at i*8192 u16: A 128x32 at +0, B 128x32 at +4096
  // epilogue reuses [0, 18432) as 4 wave-private [64][72] tiles
  __shared__ __align__(16) u16 smem[24576];
  const int tid = threadIdx.x;
  const int lane = tid & 63, wave = tid >> 6;
  const int wm = wave >> 1, wn = wave & 1;
  const int l15 = lane & 15, lg = lane >> 4;

  // grid 1152 = 8 XCD x (8 m-tiles x 18 n-tiles)
  const int bid = blockIdx.x;
  const int xcd = bid & 7, idx = bid >> 3;          // idx 0..143
  const int m0 = (xcd * 8 + idx / 18) * 128;
  const int n0g = (idx % 18) * 128;                 // 0..2176
  const int z = n0g / 768, j0 = n0g % 768;
  const u16* wz = wt + (size_t)z * 768 * 768;

  f32x4 acc[4][4] = {};

  auto stage = [&](int buf, int kt) {               // 4 gl_lds16 per thread
#pragma unroll
    for (int c = 0; c < 2; c++) {                   // A: 512 chunks
      int ci = c * 256 + tid;
      int row = ci >> 2, cp = ci & 3;
      int sc = cp ^ ((row >> 1) & 3);               // involution f(row)
      gl_lds16(&x[(size_t)(m0 + row) * 768 + kt + sc * 8],
               &smem[buf * 8192 + (c * 256 + wave * 64) * 8]);
    }
#pragma unroll
    for (int c = 0; c < 2; c++) {                   // B: 512 chunks
      int ci = c * 256 + tid;
      int row = ci >> 2, cp = ci & 3;
      int sc = cp ^ ((row >> 1) & 3);
      gl_lds16(&wz[(size_t)(j0 + row) * 768 + kt + sc * 8],
               &smem[buf * 8192 + 4096 + (c * 256 + wave * 64) * 8]);
    }
  };

  stage(0, 0);
  stage(1, 32);
  const int kc = lg ^ ((l15 >> 1) & 3);             // swizzled k-chunk for reads
  int cur = 0;
  for (int t = 0; t < 24; t++) {
    if (t < 23) { asm volatile("s_waitcnt vmcnt(4)" ::: "memory"); }
    else       { asm volatile("s_waitcnt vmcnt(0)" ::: "memory"); }
    __builtin_amdgcn_s_barrier();
    __builtin_amdgcn_sched_barrier(0);
    if (t < 22) {
      int st = cur + 2; if (st >= 3) st -= 3;
      stage(st, (t + 2) * 32);
    }
    const int base = cur * 8192;
    short8 a[4], b[4];
#pragma unroll
    for (int mf = 0; mf < 4; mf++)
      a[mf] = *(const short8*)&smem[base + (wm * 64 + mf * 16 + l15) * 32 + kc * 8];
#pragma unroll
    for (int nf = 0; nf < 4; nf++)
      b[nf] = *(const short8*)&smem[base + 4096 + (wn * 64 + nf * 16 + l15) * 32 + kc * 8];
#pragma unroll
    for (int mf = 0; mf < 4; mf++)
#pragma unroll
      for (int nf = 0; nf < 4; nf++)
        acc[mf][nf] = __builtin_amdgcn_mfma_f32_16x16x32_bf16(a[mf], b[nf], acc[mf][nf], 0, 0, 0);
    cur = (cur + 1 == 3) ? 0 : cur + 1;
  }
  __syncthreads();   // all MFMAs/reads of buf2 done before smem reuse

  // ---- epilogue: retile through wave-private LDS [64][72], 16B stores ----
  u16* ep = &smem[wave * 4608];
  const float* bias_p = (z == 0) ? bq : (z == 1 ? bk : bv);
  const float sc_ = (z == 0) ? 0.125f : 1.0f;
  const int r8 = lane >> 3, cn = lane & 7;
  if (z < 2) {
    u16* t = (z == 0) ? qb : kb;
#pragma unroll
    for (int mf = 0; mf < 4; mf++)
#pragma unroll
      for (int nf = 0; nf < 4; nf++) {
        float bias = bias_p[j0 + wn * 64 + nf * 16 + l15];
#pragma unroll
        for (int r = 0; r < 4; r++)
          ep[(mf * 16 + lg * 4 + r) * 72 + nf * 16 + l15] =
              f2bf((acc[mf][nf][r] + bias) * sc_);
      }
#pragma unroll
    for (int i = 0; i < 8; i++) {
      int rl = i * 8 + r8;                     // local m row 0..63
      short8 v = *(const short8*)&ep[rl * 72 + cn * 8];
      *(short8*)&t[(size_t)(m0 + wm * 64 + rl) * 768 + j0 + wn * 64 + cn * 8] = v;
    }
  } else {
    // build n-major tile [64 n][64 m] so the transposed vt store is contiguous
#pragma unroll
    for (int nf = 0; nf < 4; nf++) {
      float bias = bias_p[j0 + wn * 64 + nf * 16 + l15];
#pragma unroll
      for (int mf = 0; mf < 4; mf++) {
        ushort4 pk;
        pk.x = f2bf(acc[mf][nf][0] + bias);
        pk.y = f2bf(acc[mf][nf][1] + bias);
        pk.z = f2bf(acc[mf][nf][2] + bias);
        pk.w = f2bf(acc[mf][nf][3] + bias);
        *(ushort4*)&ep[(nf * 16 + l15) * 72 + mf * 16 + lg * 4] = pk;
      }
    }
#pragma unroll
    for (int i = 0; i < 8; i++) {
      int nl = i * 8 + r8;                     // local n row 0..63
      int n = j0 + wn * 64 + nl;
      int h = n >> 6, d = n & 63;
      const int bb = m0 >> 12, srow = m0 & 4095;
      short8 v = *(const short8*)&ep[nl * 72 + cn * 8];
      *(short8*)&vt[(((size_t)(bb * 12 + h) * 64 + d) << 12) +
                    srow + wm * 64 + cn * 8] = v;
    }
  }
}

// Banded attention, 4 waves/block, 128 q-rows/block, K/V staged in LDS via
// global_load_lds (reverted from R10's direct-global: scattered 16-line
// per-wave fragment loads at ~3 waves/SIMD cost +20us). T3-minimum schedule:
// {stage(next) -> compute(cur) -> ONE __syncthreads}/iter. P-store uses
// 1-op truncation (P>0; rel bias 2^-9, numerator-only).
// qb/kb: [b*S+s][h*64+d] bf16 ; vt: [((b*12+h)*64+d)][s] bf16 ; out: (S,B,E) f32
__global__ __launch_bounds__(256) void k_attn(const u16* __restrict__ qb,
                                              const u16* __restrict__ kb,
                                              const u16* __restrict__ vt,
                                              float* __restrict__ out) {
  __shared__ __align__(16) u16 Ks[2][64 * 64];
  __shared__ __align__(16) u16 Vs[2][64 * 64];
  __shared__ __align__(16) u16 pl[4][32 * 72];
  const int tid = threadIdx.x;
  const int lane = tid & 63, wave = tid >> 6;
  const int l15 = lane & 15, lg = lane >> 4;

  const int bid = blockIdx.x;            // 0..767
  const int xcd = bid & 7, i = bid >> 3; // i: 0..95
  const int pair = xcd * 3 + (i >> 5);   // 0..23
  const int chunk = i & 31;
  const int b = pair / 12, h = pair % 12;
  const int s0 = chunk * 128;
  const int q0 = s0 + wave * 32;

  short8 qf[2][2];
#pragma unroll
  for (int mf = 0; mf < 2; mf++)
#pragma unroll
    for (int ks = 0; ks < 2; ks++)
      qf[mf][ks] = *(const short8*)&qb[(size_t)((b << 12) + q0 + mf * 16 + l15) * 768 +
                                       h * 64 + ks * 32 + lg * 8];

  f32x4 o[2][4] = {};
  float lsum[2][4] = {};

  int t0 = s0 - 256; if (t0 < 0) t0 = 0;
  int t1 = s0 + 320; if (t1 > 4032) t1 = 4032;

  auto stage = [&](int buf, int kb0) {
#pragma unroll
    for (int c = 0; c < 2; c++) {
      int ci = c * 256 + tid;            // 0..511 : row=ci>>3, chunk=ci&7
      int row = ci >> 3, cc = ci & 7;
      int sc = cc ^ (row & 7);           // XOR swizzle (source-side)
      gl_lds16(&kb[(size_t)((b << 12) + kb0 + row) * 768 + h * 64 + sc * 8],
               &Ks[buf][(c * 256 + wave * 64) * 8]);
      gl_lds16(&vt[((size_t)((b * 12 + h) * 64 + row) << 12) + kb0 + sc * 8],
               &Vs[buf][(c * 256 + wave * 64) * 8]);
    }
  };

  // prologue: stage tile 0 and drain once
  stage(0, t0);
  __syncthreads();

  int buf = 0;
  for (int kb0 = t0; kb0 <= t1; kb0 += 64) {
    if (kb0 + 64 <= t1) stage(buf ^ 1, kb0 + 64);   // issue early
    const bool act = (kb0 + 63 >= q0 - 256) && (kb0 <= q0 + 31 + 256);
    if (act) {
      f32x4 sf[2][4] = {};
#pragma unroll
      for (int ks = 0; ks < 2; ks++) {
        short8 bkf[4];
#pragma unroll
        for (int nf = 0; nf < 4; nf++) {
          int row = nf * 16 + l15;
          bkf[nf] = *(const short8*)&Ks[buf][row * 64 + (((ks * 4 + lg) ^ (row & 7)) * 8)];
        }
#pragma unroll
        for (int mf = 0; mf < 2; mf++)
#pragma unroll
          for (int nf = 0; nf < 4; nf++)
            sf[mf][nf] = __builtin_amdgcn_mfma_f32_16x16x32_bf16(qf[mf][ks], bkf[nf], sf[mf][nf], 0, 0, 0);
      }
      if (kb0 < q0 - 192 || kb0 > q0 + 192) {
#pragma unroll
        for (int mf = 0; mf < 2; mf++)
#pragma unroll
          for (int nf = 0; nf < 4; nf++) {
            int kj = kb0 + nf * 16 + l15;
#pragma unroll
            for (int r = 0; r < 4; r++) {
              int qi = q0 + mf * 16 + lg * 4 + r;
              if ((unsigned)(kj - qi + 256) > 512u) sf[mf][nf][r] = -3e38f;
            }
          }
      }
      u16* plw = pl[wave];
#pragma unroll
      for (int mf = 0; mf < 2; mf++)
#pragma unroll
        for (int nf = 0; nf < 4; nf++)
#pragma unroll
          for (int r = 0; r < 4; r++) {
            float p = __expf(sf[mf][nf][r]);
            lsum[mf][r] += p;
            plw[(mf * 16 + lg * 4 + r) * 72 + nf * 16 + l15] = f2bf_trunc(p);
          }
      short8 pa[2][2];
#pragma unroll
      for (int mf = 0; mf < 2; mf++)
#pragma unroll
        for (int ks = 0; ks < 2; ks++)
          pa[mf][ks] = *(const short8*)&plw[(mf * 16 + l15) * 72 + ks * 32 + lg * 8];
#pragma unroll
      for (int ks = 0; ks < 2; ks++) {
        short8 bvf[4];
#pragma unroll
        for (int df = 0; df < 4; df++) {
          int row = df * 16 + l15;
          bvf[df] = *(const short8*)&Vs[buf][row * 64 + (((ks * 4 + lg) ^ (row & 7)) * 8)];
        }
#pragma unroll
        for (int mf = 0; mf < 2; mf++)
#pragma unroll
          for (int df = 0; df < 4; df++)
            o[mf][df] = __builtin_amdgcn_mfma_f32_16x16x32_bf16(pa[mf][ks], bvf[df], o[mf][df], 0, 0, 0);
      }
    }
    __syncthreads();   // ONE barrier/iter: drains vm+lgkm after compute
    buf ^= 1;
  }

#pragma unroll
  for (int mf = 0; mf < 2; mf++)
#pragma unroll
    for (int r = 0; r < 4; r++) {
      float l = lsum[mf][r];
      l += __shfl_xor(l, 1); l += __shfl_xor(l, 2);
      l += __shfl_xor(l, 4); l += __shfl_xor(l, 8);
      lsum[mf][r] = l;
    }

#pragma unroll
  for (int mf = 0; mf < 2; mf++)
#pragma unroll
    for (int df = 0; df < 4; df++)
#pragma unroll
      for (int r = 0; r < 4; r++) {
        int s = q0 + mf * 16 + lg * 4 + r;
        out[(size_t)(s * 2 + b) * 768 + h * 64 + df * 16 + l15] =
            o[mf][df][r] / lsum[mf][r];
      }
}

extern "C" void kernel_launch(void* const* d_in, const int* in_sizes, int n_in,
                              void* d_out, int out_size, void* d_ws, size_t ws_size,
                              hipStream_t stream) {
  const float* query = (const float*)d_in[0];
  const float* Wq = (const float*)d_in[1];
  const float* bq = (const float*)d_in[2];
  const float* Wk = (const float*)d_in[3];
  const float* bk = (const float*)d_in[4];
  const float* Wv = (const float*)d_in[5];
  const float* bv = (const float*)d_in[6];
  float* out = (float*)d_out;

  char* ws = (char*)d_ws;
  size_t off = 0;
  auto alloc = [&](size_t bytes) {
    void* p = ws + off;
    off = (off + bytes + 255) & ~(size_t)255;
    return p;
  };
  u16* x  = (u16*)alloc((size_t)8192 * 768 * 2);
  u16* wt = (u16*)alloc((size_t)3 * 768 * 768 * 2);
  u16* qb = (u16*)alloc((size_t)8192 * 768 * 2);
  u16* kb = (u16*)alloc((size_t)8192 * 768 * 2);
  u16* vt = (u16*)alloc((size_t)8192 * 768 * 2);

  hipLaunchKernelGGL(k_prep, dim3(1728 + 8192), dim3(256), 0, stream,
                     query, Wq, Wk, Wv, x, wt);
  hipLaunchKernelGGL(k_gemm_qkv, dim3(1152), dim3(256), 0, stream,
                     x, wt, bq, bk, bv, qb, kb, vt);
  hipLaunchKernelGGL(k_attn, dim3(768), dim3(256), 0, stream, qb, kb, vt, out);
}